// Round 1
// 439.488 us; speedup vs baseline: 1.0174x; 1.0174x over previous
//
#include <hip/hip_runtime.h>
#include <cstdint>
#include <cstddef>

#define NNODES 50000
#define NEDGES 800000
#define DH1    256   // H*HID = 4*64
#define DOUT   128

// exp-domain folding constants: leaky(m)·att = 0.6*ssum + 0.4*Σatt|m|,
// exp(x) = exp2(x*log2e) -> fold log2e into the 0.6/0.4 scales at the producers.
#define K1F 0.8656170245333781f   // 0.6 * log2(e)
#define K2F 0.5770780163555854f   // 0.4 * log2(e)

typedef unsigned short u16;
typedef __bf16 bf16x8 __attribute__((ext_vector_type(8)));
typedef float  f32x4  __attribute__((ext_vector_type(4)));

__device__ __forceinline__ float bf2f(unsigned int u) {
  union { unsigned int i; float f; } x; x.i = u << 16; return x.f;
}
__device__ __forceinline__ u16 f2bf(float f) {
  union { float f; unsigned int i; } x; x.f = f;
  unsigned int r = x.i + 0x7fffu + ((x.i >> 16) & 1u);  // round-to-nearest-even
  return (u16)(r >> 16);
}
__device__ __forceinline__ void dec8(uint4 r, float* o) {
  o[0] = bf2f(r.x & 0xffffu); o[1] = bf2f(r.x >> 16);
  o[2] = bf2f(r.y & 0xffffu); o[3] = bf2f(r.y >> 16);
  o[4] = bf2f(r.z & 0xffffu); o[5] = bf2f(r.z >> 16);
  o[6] = bf2f(r.w & 0xffffu); o[7] = bf2f(r.w >> 16);
}
__device__ __forceinline__ uint4 pack8(const float* v) {
  uint4 p;
  p.x = (unsigned)f2bf(v[0]) | ((unsigned)f2bf(v[1]) << 16);
  p.y = (unsigned)f2bf(v[2]) | ((unsigned)f2bf(v[3]) << 16);
  p.z = (unsigned)f2bf(v[4]) | ((unsigned)f2bf(v[5]) << 16);
  p.w = (unsigned)f2bf(v[6]) | ((unsigned)f2bf(v[7]) << 16);
  return p;
}
// pure-VALU cross-lane add via DPP (replaces ds_swizzle: no LDS pipe, no lgkmcnt stall)
// 0xB1 = quad_perm [1,0,3,2] (lane^1), 0x4E = quad_perm [2,3,0,1] (lane^2),
// 0x141 = row_half_mirror (partner quad within 8-group), 0x140 = row_mirror (partner 8-group in row)
template<int CTRL>
__device__ __forceinline__ float dppadd(float v) {
  int t = __builtin_amdgcn_update_dpp(0, __float_as_int(v), CTRL, 0xF, 0xF, true);
  return v + __int_as_float(t);
}
__device__ __forceinline__ float fexp2(float x) {
#if __has_builtin(__builtin_amdgcn_exp2f)
  return __builtin_amdgcn_exp2f(x);
#else
  return exp2f(x);
#endif
}

// ---------------- setup: rank-count + cvt + weight-prep + att*We + epair pad ----------------

#define CNT_BLKS 3125
#define CVT_BLKS 6250
#define W1_BLKS  320
#define W2_BLKS  256

__global__ __launch_bounds__(256) void setup_k(
    const int* __restrict__ dst, int* __restrict__ cnt, int* __restrict__ rank,
    const float* __restrict__ x, u16* __restrict__ xbf,
    const float* __restrict__ Wl1, const float* __restrict__ Wr1,
    const float* __restrict__ bl1, const float* __restrict__ br1,
    const float* __restrict__ Wl2, const float* __restrict__ Wr2,
    const float* __restrict__ bl2, const float* __restrict__ br2,
    const float* __restrict__ skW, const float* __restrict__ skb,
    const float* __restrict__ att1, const float* __restrict__ We1,
    const float* __restrict__ att2, const float* __restrict__ We2,
    u16* __restrict__ Wcat1, float* __restrict__ bias1,
    u16* __restrict__ Wt2, float* __restrict__ bias2,
    float* __restrict__ axw, int2* __restrict__ epair) {
  int b = blockIdx.x, t = threadIdx.x;
  if (b < CNT_BLKS) {
    int e = b * 256 + t;
    if (e < NEDGES) rank[e] = atomicAdd(&cnt[dst[e]], 1);
  } else if (b < CNT_BLKS + CVT_BLKS) {
    int i = ((b - CNT_BLKS) * 256 + t) * 4;
    float4 v = *reinterpret_cast<const float4*>(x + i);
    uint2 pk;
    pk.x = (unsigned)f2bf(v.x) | ((unsigned)f2bf(v.y) << 16);
    pk.y = (unsigned)f2bf(v.z) | ((unsigned)f2bf(v.w) << 16);
    *reinterpret_cast<uint2*>(xbf + i) = pk;
  } else if (b < CNT_BLKS + CVT_BLKS + W1_BLKS) {
    int idx = (b - CNT_BLKS - CVT_BLKS) * 256 + t;   // 640 x 128
    if (idx < 640) bias1[idx] = idx < 256 ? bl1[idx] : idx < 512 ? br1[idx - 256] : skb[idx - 512];
    int n = idx >> 7, k = idx & 127;
    float v = n < 256 ? Wl1[k * 256 + n] : n < 512 ? Wr1[k * 256 + (n - 256)] : skW[k * 128 + (n - 512)];
    Wcat1[idx] = f2bf(v);
  } else if (b < CNT_BLKS + CVT_BLKS + W1_BLKS + W2_BLKS) {
    int idx = (b - CNT_BLKS - CVT_BLKS - W1_BLKS) * 256 + t;  // 256 x 256
    if (idx < 256) bias2[idx] = idx < 128 ? bl2[idx] : br2[idx - 128];
    int n = idx >> 8, k = idx & 255;
    float v = n < 128 ? Wl2[k * 128 + n] : Wr2[k * 128 + (n - 128)];
    Wt2[idx] = f2bf(v);
  } else if (b == CNT_BLKS + CVT_BLKS + W1_BLKS + W2_BLKS) {
    if (t < 4) {
      float s = 0.f;
      for (int c = 0; c < 64; ++c) s += att1[t * 64 + c] * We1[t * 64 + c];
      axw[t] = s * K1F;
    } else if (t == 4) {
      float s = 0.f;
      for (int c = 0; c < 128; ++c) s += att2[c] * We2[c];
      axw[4] = s * K1F;
    }
  } else {
    // zero the epair padding (enables clamp-free prefetch in gat_edge)
    int2 z; z.x = 0; z.y = 0;
    epair[NEDGES + t] = z;
  }
}

// ---------------- CSR ----------------

__global__ __launch_bounds__(256) void offsets_k(const int* __restrict__ cnt, int* __restrict__ offs,
                                                 int* __restrict__ total) {
  int i = blockIdx.x * 256 + threadIdx.x;
  int lane = threadIdx.x & 63;
  int c = (i < NNODES) ? cnt[i] : 0;
  int incl = c;
  #pragma unroll
  for (int d = 1; d < 64; d <<= 1) {
    int t = __shfl_up(incl, d, 64);
    if (lane >= d) incl += t;
  }
  int wtotal = __shfl(incl, 63, 64);
  int base = 0;
  if (lane == 63) base = atomicAdd(total, wtotal);
  base = __shfl(base, 63, 64);
  int off = base + incl - c;
  if (i < NNODES) offs[i] = off;
}

__global__ __launch_bounds__(256) void scatter_k(const int* __restrict__ src, const int* __restrict__ dst,
                                                 const float* __restrict__ ea, const int* __restrict__ offs,
                                                 const int* __restrict__ rank, int2* __restrict__ epair) {
  int e = blockIdx.x * 256 + threadIdx.x;
  if (e >= NEDGES) return;
  int p = offs[dst[e]] + rank[e];
  int2 v; v.x = src[e]; v.y = __float_as_int(ea[e]);
  epair[p] = v;
}

// ---------------- MFMA GEMM: stage A once, loop NPASS col-blocks internally ----------------
// C routing: [0,B1)->C0, [B1,B2)->C1, [B2,..)->C2 (bf16). Optional fused BN+PReLU on A.
// Optional att-dot epilogue (cols < B2): ax[row, head] = K1F * sum att[c]*C[row,c] per SPAN block.

template<int K, int NPASS, int B1, int B2, int LDC0, int LDC1, int LDC2,
         int SPAN, int ATTLEN, bool DO_ATT, bool FUSE_BN>
__global__ __launch_bounds__(512) void gemm_fused(
    const u16* __restrict__ A, const u16* __restrict__ Wt, const float* __restrict__ bias,
    u16* __restrict__ C0, u16* __restrict__ C1, u16* __restrict__ C2,
    const float* __restrict__ att, float* __restrict__ axl, float* __restrict__ axr,
    const float* __restrict__ bnsum, const float* __restrict__ bnsq,
    const float* __restrict__ bng, const float* __restrict__ bnb,
    const float* __restrict__ pap) {
  constexpr int LDA = K + 8;
  constexpr int CSTR = 136;
  __shared__ __align__(16) u16 As[64 * LDA];
  __shared__ __align__(16) u16 Cs[64 * CSTR];
  __shared__ float attS[128];
  __shared__ float scS[K], shS[K];
  const int tid = threadIdx.x;
  const int row0 = blockIdx.x * 64;

  if constexpr (FUSE_BN) {
    if (tid < K) {
      const float invN = 1.0f / (float)NNODES;
      float mu = bnsum[tid] * invN;
      float var = bnsq[tid] * invN - mu * mu;
      float s = bng[tid] * rsqrtf(var + 1e-5f);
      scS[tid] = s;
      shS[tid] = bnb[tid] - mu * s;
    }
    __syncthreads();
  }
  const float pa = FUSE_BN ? pap[0] : 0.f;
  // stage A (64 x K bf16)
  #pragma unroll
  for (int it = 0; it < K / 32; ++it) {
    int chunk = it * 512 + tid;
    int row = chunk / (K / 4);
    int col = (chunk % (K / 4)) * 4;
    uint2 v; v.x = 0u; v.y = 0u;
    int gr = row0 + row;
    if (gr < NNODES) v = *reinterpret_cast<const uint2*>(A + (size_t)gr * K + col);
    if constexpr (FUSE_BN) {
      float o0 = bf2f(v.x & 0xffffu) * scS[col]     + shS[col];
      float o1 = bf2f(v.x >> 16)     * scS[col + 1] + shS[col + 1];
      float o2 = bf2f(v.y & 0xffffu) * scS[col + 2] + shS[col + 2];
      float o3 = bf2f(v.y >> 16)     * scS[col + 3] + shS[col + 3];
      o0 = o0 > 0.f ? o0 : pa * o0;
      o1 = o1 > 0.f ? o1 : pa * o1;
      o2 = o2 > 0.f ? o2 : pa * o2;
      o3 = o3 > 0.f ? o3 : pa * o3;
      v.x = (unsigned)f2bf(o0) | ((unsigned)f2bf(o1) << 16);
      v.y = (unsigned)f2bf(o2) | ((unsigned)f2bf(o3) << 16);
    }
    *reinterpret_cast<uint2*>(&As[row * LDA + col]) = v;
  }
  __syncthreads();

  const int w = tid >> 6, lane = tid & 63, q = lane >> 4, l16 = lane & 15;
  const int tc = w * 16 + l16;

  #pragma unroll
  for (int p = 0; p < NPASS; ++p) {
    const int cb = p * 128;
    const int ncol = cb + tc;
    f32x4 acc[4];
    #pragma unroll
    for (int rt = 0; rt < 4; ++rt) acc[rt] = (f32x4){0.f, 0.f, 0.f, 0.f};
    const u16* wp = Wt + (size_t)ncol * K + q * 8;
    #pragma unroll
    for (int ks = 0; ks < K / 32; ++ks) {
      bf16x8 b = *reinterpret_cast<const bf16x8*>(wp + ks * 32);
      #pragma unroll
      for (int rt = 0; rt < 4; ++rt) {
        bf16x8 a = *reinterpret_cast<const bf16x8*>(&As[(rt * 16 + l16) * LDA + ks * 32 + q * 8]);
        acc[rt] = __builtin_amdgcn_mfma_f32_16x16x32_bf16(a, b, acc[rt], 0, 0, 0);
      }
    }
    const float bval = bias[ncol];
    #pragma unroll
    for (int rt = 0; rt < 4; ++rt)
      #pragma unroll
      for (int r = 0; r < 4; ++r)
        Cs[(rt * 16 + q * 4 + r) * CSTR + tc] = f2bf(acc[rt][r] + bval);
    if (DO_ATT && cb < B2 && tid < 128) attS[tid] = att[(cb + tid) % ATTLEN];
    __syncthreads();
    // coalesced C store
    {
      u16* Cg; int LD, cc;
      if (cb < B1)      { Cg = C0; LD = LDC0; cc = cb; }
      else if (cb < B2) { Cg = C1; LD = LDC1; cc = cb - B1; }
      else              { Cg = C2; LD = LDC2; cc = cb - B2; }
      #pragma unroll
      for (int it = 0; it < 2; ++it) {
        int ch = it * 512 + tid;
        int row = ch / 16, co = (ch % 16) * 8;
        int grow = row0 + row;
        if (grow < NNODES) {
          uint4 v = *reinterpret_cast<const uint4*>(&Cs[row * CSTR + co]);
          *reinterpret_cast<uint4*>(Cg + (size_t)grow * LD + cc + co) = v;
        }
      }
    }
    // att-dot: parallel (SPAN/16 threads per (row, head)), shfl-reduced
    if constexpr (DO_ATT) {
      if (cb < B2) {
        constexpr int TPU = SPAN / 16;     // threads per unit (4 or 8)
        constexpr int HIT = 128 / SPAN;    // heads in tile (2 or 1)
        constexpr int HEADS = B1 / SPAN;
        int unit = tid / TPU, sub = tid % TPU;
        int row = unit / HIT, hb = unit % HIT;
        int c0 = hb * SPAN + sub * 16;
        float s = 0.f;
        #pragma unroll
        for (int c = 0; c < 16; ++c)
          s += bf2f(Cs[row * CSTR + c0 + c]) * attS[c0 + c];
        #pragma unroll
        for (int d = 1; d < TPU; d <<= 1) s += __shfl_xor(s, d, 64);
        int grow = row0 + row;
        if (sub == 0 && grow < NNODES) {
          int cbl = cb < B1 ? cb : cb - B1;
          int head = cbl / SPAN + hb;
          float* dstp = (cb < B1) ? axl : axr;
          dstp[grow * HEADS + head] = s * K1F;   // pre-scale into log2 domain for gat_edge
        }
      }
    }
    __syncthreads();   // Cs reused next pass
  }
}

// ---------------- GATv2 edge pass: EPW edges/wave, CPL=8, clamp-free pipeline ----------------
// score(log2) = axl'[src] + axr'[dst] + ea*aWe' + sum((K2*att)*|m|) ; e = exp2(score)
// (axl/axr/aWe pre-scaled by K1F at producers; att scaled by K2F at load)

template<int HEADS, int CHAN, int EPW>
__global__ __launch_bounds__(256) void gat_edge(
    const int* __restrict__ offs, const int* __restrict__ cnt,
    const int2* __restrict__ epair,
    const u16* __restrict__ xl, const u16* __restrict__ xr,
    const float* __restrict__ att, const float* __restrict__ We,
    const float* __restrict__ cb,
    const float* __restrict__ axl, const float* __restrict__ axr,
    const float* __restrict__ aWep, u16* __restrict__ hout) {
  constexpr int HC  = HEADS * CHAN;
  constexpr int GSZ = 64 / EPW;       // lanes per edge group
  constexpr int CPL = HC / GSZ;       // channels per lane
  constexpr int LPH = CHAN / CPL;     // lanes per head cluster
  static_assert(CPL == 8, "layout");

  int node = __builtin_amdgcn_readfirstlane((int)(blockIdx.x * 4 + (threadIdx.x >> 6)));
  if (node >= NNODES) return;
  const int lane = threadIdx.x & 63;
  const int g    = lane / GSZ;
  const int lgs  = lane & (GSZ - 1);
  const int h    = lgs / LPH;
  const int cbase = lgs * CPL;

  float xrv[8], attv[8], wev[8];
  {
    uint4 xrr = *reinterpret_cast<const uint4*>(xr + (size_t)node * HC + cbase);
    dec8(xrr, xrv);
    float4 a0 = *reinterpret_cast<const float4*>(att + cbase);
    float4 a1 = *reinterpret_cast<const float4*>(att + cbase + 4);
    float4 w0 = *reinterpret_cast<const float4*>(We + cbase);
    float4 w1 = *reinterpret_cast<const float4*>(We + cbase + 4);
    attv[0]=a0.x*K2F; attv[1]=a0.y*K2F; attv[2]=a0.z*K2F; attv[3]=a0.w*K2F;
    attv[4]=a1.x*K2F; attv[5]=a1.y*K2F; attv[6]=a1.z*K2F; attv[7]=a1.w*K2F;
    wev[0]=w0.x; wev[1]=w0.y; wev[2]=w0.z; wev[3]=w0.w;
    wev[4]=w1.x; wev[5]=w1.y; wev[6]=w1.z; wev[7]=w1.w;
  }
  const float aWe = aWep[h];                  // pre-scaled by K1F
  const float axr_n = axr[node * HEADS + h];  // pre-scaled by K1F
  const int off = __builtin_amdgcn_readfirstlane(offs[node]);
  const int deg = __builtin_amdgcn_readfirstlane(cnt[node]);

  // 32-bit byte offsets (all gather regions < 2^31 bytes) -> saddr-form loads, no 64b addr math
  const char* __restrict__ xlb  = (const char*)xl;
  const char* __restrict__ axlb = (const char*)axl;
  const unsigned cboff = (unsigned)(cbase * 2);
  const unsigned hoff  = (unsigned)(h * 4);

  float den = 0.f;
  float accv[8];
  #pragma unroll
  for (int c = 0; c < 8; ++c) accv[c] = 0.f;

  const int niter = (deg + EPW - 1) / EPW;
  const int2* pp = epair + off + g;       // lane's edge stream; over-reads land in zeroed pad
  // depth-3 epair / depth-2 row+ax prefetch pipeline
  int2 p0 = pp[0];
  int2 p1 = pp[EPW];
  int2 p2 = pp[2 * EPW];
  uint4 r0, r1; float ax0, ax1;
  {
    unsigned b0 = (unsigned)p0.x * (unsigned)(HC * 2) + cboff;
    r0  = *reinterpret_cast<const uint4*>(xlb + b0);
    ax0 = *reinterpret_cast<const float*>(axlb + ((unsigned)p0.x * (unsigned)(HEADS * 4) + hoff));
    unsigned b1 = (unsigned)p1.x * (unsigned)(HC * 2) + cboff;
    r1  = *reinterpret_cast<const uint4*>(xlb + b1);
    ax1 = *reinterpret_cast<const float*>(axlb + ((unsigned)p1.x * (unsigned)(HEADS * 4) + hoff));
  }
  const int lastg = deg - 1 - (niter - 1) * EPW;   // valid-g bound, final iteration only
  for (int i = 0; i < niter; ++i) {
    int2 p3 = pp[(i + 3) * EPW];
    uint4 r2; float ax2;
    {
      unsigned b2 = (unsigned)p2.x * (unsigned)(HC * 2) + cboff;
      r2  = *reinterpret_cast<const uint4*>(xlb + b2);
      ax2 = *reinterpret_cast<const float*>(axlb + ((unsigned)p2.x * (unsigned)(HEADS * 4) + hoff));
    }
    float ea = __int_as_float(p0.y);
    float xlv[8];
    dec8(r0, xlv);
    float part2 = 0.f;
    #pragma unroll
    for (int c = 0; c < 8; ++c) {
      float m = xlv[c] + fmaf(ea, wev[c], xrv[c]);
      part2 = fmaf(fabsf(m), attv[c], part2);
    }
    // pure-VALU butterfly within the LPH-lane head cluster (no ds_swizzle / lgkm stalls)
    if constexpr (LPH >= 2)  part2 = dppadd<0xB1>(part2);   // lane^1
    if constexpr (LPH >= 4)  part2 = dppadd<0x4E>(part2);   // lane^2
    if constexpr (LPH >= 8)  part2 = dppadd<0x141>(part2);  // row_half_mirror: partner quad
    if constexpr (LPH >= 16) part2 = dppadd<0x140>(part2);  // row_mirror: partner 8-group
    float e = fexp2(part2 + fmaf(ea, aWe, axr_n) + ax0);
    if (i == niter - 1) e = (g <= lastg) ? e : 0.f;   // uniform branch; mask only in tail iter
    den += e;
    #pragma unroll
    for (int c = 0; c < 8; ++c) accv[c] = fmaf(e, xlv[c], accv[c]);
    p0 = p1; p1 = p2; p2 = p3; r0 = r1; r1 = r2; ax0 = ax1; ax1 = ax2;
  }
  #pragma unroll
  for (int d = GSZ; d < 64; d <<= 1) {
    den += __shfl_xor(den, d, 64);
    #pragma unroll
    for (int c = 0; c < 8; ++c) accv[c] += __shfl_xor(accv[c], d, 64);
  }
  if (g == 0) {
    float inv = 1.0f / (den + 1e-16f);
    float4 c0 = *reinterpret_cast<const float4*>(cb + cbase);
    float4 c1 = *reinterpret_cast<const float4*>(cb + cbase + 4);
    float ov[8];
    ov[0] = accv[0] * inv + c0.x; ov[1] = accv[1] * inv + c0.y;
    ov[2] = accv[2] * inv + c0.z; ov[3] = accv[3] * inv + c0.w;
    ov[4] = accv[4] * inv + c1.x; ov[5] = accv[5] * inv + c1.y;
    ov[6] = accv[6] * inv + c1.z; ov[7] = accv[7] * inv + c1.w;
    *reinterpret_cast<uint4*>(hout + (size_t)node * HC + cbase) = pack8(ov);
  }
}

// ---------------- BatchNorm ----------------

template<int NC>
__global__ void bn_stats_bf(const u16* __restrict__ h, float* __restrict__ sum, float* __restrict__ sq) {
  int c = threadIdx.x;
  float s = 0.f, q = 0.f;
  for (int r = blockIdx.x; r < NNODES; r += gridDim.x) {
    float v = bf2f(h[(size_t)r * NC + c]);
    s += v; q += v * v;
  }
  atomicAdd(&sum[c], s);
  atomicAdd(&sq[c], q);
}

__global__ __launch_bounds__(256) void final_out_k(
    const u16* __restrict__ h2, const u16* __restrict__ skip,
    const float* __restrict__ sum, const float* __restrict__ sq,
    const float* __restrict__ g, const float* __restrict__ bb_,
    const float* __restrict__ pap, float* __restrict__ outp, int total) {
  int i = (blockIdx.x * 256 + threadIdx.x) * 4;
  if (i >= total) return;
  const float invN = 1.0f / (float)NNODES;
  float pa = pap[0];
  int c = i & 127;
  float4 sm = *reinterpret_cast<const float4*>(sum + c);
  float4 qq = *reinterpret_cast<const float4*>(sq + c);
  float4 gg = *reinterpret_cast<const float4*>(g + c);
  float4 bb = *reinterpret_cast<const float4*>(bb_ + c);
  float mu, var, sc[4], sh[4];
  mu = sm.x * invN; var = qq.x * invN - mu * mu; sc[0] = gg.x * rsqrtf(var + 1e-5f); sh[0] = bb.x - mu * sc[0];
  mu = sm.y * invN; var = qq.y * invN - mu * mu; sc[1] = gg.y * rsqrtf(var + 1e-5f); sh[1] = bb.y - mu * sc[1];
  mu = sm.z * invN; var = qq.z * invN - mu * mu; sc[2] = gg.z * rsqrtf(var + 1e-5f); sh[2] = bb.z - mu * sc[2];
  mu = sm.w * invN; var = qq.w * invN - mu * mu; sc[3] = gg.w * rsqrtf(var + 1e-5f); sh[3] = bb.w - mu * sc[3];
  uint2 raw = *reinterpret_cast<const uint2*>(h2 + i);
  float v0 = bf2f(raw.x & 0xffffu), v1 = bf2f(raw.x >> 16);
  float v2 = bf2f(raw.y & 0xffffu), v3 = bf2f(raw.y >> 16);
  uint2 skr = *reinterpret_cast<const uint2*>(skip + i);
  float s0 = bf2f(skr.x & 0xffffu), s1 = bf2f(skr.x >> 16);
  float s2 = bf2f(skr.y & 0xffffu), s3 = bf2f(skr.y >> 16);
  float4 o;
  o.x = v0 * sc[0] + sh[0]; o.x = (o.x > 0.f ? o.x : pa * o.x) + s0;
  o.y = v1 * sc[1] + sh[1]; o.y = (o.y > 0.f ? o.y : pa * o.y) + s1;
  o.z = v2 * sc[2] + sh[2]; o.z = (o.z > 0.f ? o.z : pa * o.z) + s2;
  o.w = v3 * sc[3] + sh[3]; o.w = (o.w > 0.f ? o.w : pa * o.w) + s3;
  *reinterpret_cast<float4*>(outp + i) = o;
}

// ---------------- launch ----------------

extern "C" void kernel_launch(void* const* d_in, const int* in_sizes, int n_in,
                              void* d_out, int out_size, void* d_ws, size_t ws_size,
                              hipStream_t stream) {
  (void)in_sizes; (void)n_in; (void)out_size; (void)ws_size;
  const float* x    = (const float*)d_in[0];
  const int*   ei   = (const int*)d_in[1];
  const float* ea   = (const float*)d_in[2];
  const float* Wl1  = (const float*)d_in[3];
  const float* bl1  = (const float*)d_in[4];
  const float* Wr1  = (const float*)d_in[5];
  const float* br1  = (const float*)d_in[6];
  const float* We1  = (const float*)d_in[7];
  const float* att1 = (const float*)d_in[8];
  const float* cb1  = (const float*)d_in[9];
  const float* bng1 = (const float*)d_in[10];
  const float* bnb1 = (const float*)d_in[11];
  const float* pa   = (const float*)d_in[12];
  const float* Wl2  = (const float*)d_in[13];
  const float* bl2  = (const float*)d_in[14];
  const float* Wr2  = (const float*)d_in[15];
  const float* br2  = (const float*)d_in[16];
  const float* We2  = (const float*)d_in[17];
  const float* att2 = (const float*)d_in[18];
  const float* cb2  = (const float*)d_in[19];
  const float* bng2 = (const float*)d_in[20];
  const float* bnb2 = (const float*)d_in[21];
  const float* skW  = (const float*)d_in[22];
  const float* skb  = (const float*)d_in[23];
  const int* srcp = ei;
  const int* dstp = ei + NEDGES;

  char* base = (char*)d_ws;
  size_t off = 0;
  auto alloc = [&](size_t bytes) -> char* {
    char* p = base + off;
    off = (off + bytes + 255) & ~(size_t)255;
    return p;
  };
  size_t zero_ints = 1 + NNODES + 256 + 256 + 128 + 128;
  char* zbase = alloc(zero_ints * 4);
  int*   totalp = (int*)zbase;
  int*   cnt    = totalp + 1;
  float* bnsum1 = (float*)(cnt + NNODES);
  float* bnsq1  = bnsum1 + 256;
  float* bnsum2 = bnsq1 + 256;
  float* bnsq2  = bnsum2 + 128;

  int*   offs    = (int*)alloc((size_t)NNODES * 4);
  int*   rank    = (int*)alloc((size_t)NEDGES * 4);
  int2*  epair   = (int2*)alloc(((size_t)NEDGES + 256) * 8);
  const size_t RBYTES = (size_t)NNODES * DH1 * 2;  // 25.6 MB
  char* regionA = alloc(RBYTES);   // xl1(bf16) -> h2(bf16)
  char* regionB = alloc(RBYTES);   // xr1(bf16) -> xl2+xr2(bf16)
  char* regionC = alloc(RBYTES);   // h1(bf16)
  u16*   xbf    = (u16*)alloc((size_t)NNODES * 128 * 2);
  u16*   skipbf = (u16*)alloc((size_t)NNODES * 128 * 2);
  u16*   Wcat1  = (u16*)alloc(640 * 128 * 2);
  u16*   Wt2    = (u16*)alloc(256 * 256 * 2);
  float* bias1  = (float*)alloc(640 * 4);
  float* bias2  = (float*)alloc(256 * 4);
  float* axw    = (float*)alloc(8 * 4);
  float* axl1   = (float*)alloc((size_t)NNODES * 4 * 4);
  float* axr1   = (float*)alloc((size_t)NNODES * 4 * 4);
  float* axl2   = (float*)alloc((size_t)NNODES * 4);
  float* axr2   = (float*)alloc((size_t)NNODES * 4);

  u16*   xl1     = (u16*)regionA;
  u16*   xr1     = (u16*)regionB;
  u16*   h1      = (u16*)regionC;
  u16*   xl2     = (u16*)regionB;
  u16*   xr2     = (u16*)(regionB + (size_t)NNODES * DOUT * 2);
  u16*   h2      = (u16*)regionA;

  hipMemsetAsync(zbase, 0, zero_ints * 4, stream);

  const int EB = (NEDGES + 255) / 256;
  const int NB = (NNODES + 255) / 256;
  setup_k<<<CNT_BLKS + CVT_BLKS + W1_BLKS + W2_BLKS + 2, 256, 0, stream>>>(
      dstp, cnt, rank, x, xbf, Wl1, Wr1, bl1, br1, Wl2, Wr2, bl2, br2, skW, skb,
      att1, We1, att2, We2, Wcat1, bias1, Wt2, bias2, axw, epair);
  offsets_k<<<NB, 256, 0, stream>>>(cnt, offs, totalp);
  scatter_k<<<EB, 256, 0, stream>>>(srcp, dstp, ea, offs, rank, epair);

  const int MB64 = (NNODES + 63) / 64;
  // layer 1 + skip: cols [0,256)=xl1, [256,512)=xr1, [512,640)=skip
  gemm_fused<128, 5, 256, 512, 256, 256, 128, 64, 256, true, false><<<MB64, 512, 0, stream>>>(
      xbf, Wcat1, bias1, xl1, xr1, skipbf, att1, axl1, axr1,
      (const float*)0, (const float*)0, (const float*)0, (const float*)0, (const float*)0);
  gat_edge<4, 64, 2><<<(NNODES + 3) / 4, 256, 0, stream>>>(
      offs, cnt, epair, xl1, xr1, att1, We1, cb1, axl1, axr1, axw, h1);
  bn_stats_bf<256><<<800, 256, 0, stream>>>(h1, bnsum1, bnsq1);

  // layer 2 (BN1+PReLU fused into A-staging): cols [0,128)=xl2, [128,256)=xr2
  gemm_fused<256, 2, 128, 256, 128, 128, 1, 128, 128, true, true><<<MB64, 512, 0, stream>>>(
      h1, Wt2, bias2, xl2, xr2, (u16*)0, att2, axl2, axr2,
      bnsum1, bnsq1, bng1, bnb1, pa);
  gat_edge<1, 128, 4><<<(NNODES + 3) / 4, 256, 0, stream>>>(
      offs, cnt, epair, xl2, xr2, att2, We2, cb2, axl2, axr2, axw + 4, h2);
  bn_stats_bf<128><<<800, 128, 0, stream>>>(h2, bnsum2, bnsq2);
  final_out_k<<<(NNODES * DOUT / 4 + 255) / 256, 256, 0, stream>>>(
      h2, skipbf, bnsum2, bnsq2, bng2, bnb2, pa, (float*)d_out, NNODES * DOUT);
}